// Round 3
// baseline (6010.711 us; speedup 1.0000x reference)
//
#include <hip/hip_runtime.h>

#define NB 256
#define CIN 32
#define HWDIM 48
#define EDIM 256
#define KF 8
#define OW 41
#define LPOS 1681
#define EPSV 1e-5f

#define NOX 21      // outputs per block half
#define WIN 28      // input window columns per block half

__device__ __forceinline__ float waveSum(float v){
#pragma unroll
  for(int o=32;o;o>>=1) v += __shfl_xor(v,o);
  return v;
}

// ---------------------------------------------------------------------------
// k_prep: gw[e] = ln1_g[e] * (sum_f bq[f]*wk[f,e]);
//         cst[0] = sum_e ln1_g[e]*wq_eff[e]; cst[1] = sum_e ln1_b[e]*wq_eff[e] + bq.bk
// ---------------------------------------------------------------------------
__global__ __launch_bounds__(256) void k_prep(const float* __restrict__ wk,
    const float* __restrict__ bq, const float* __restrict__ bk,
    const float* __restrict__ g1, const float* __restrict__ b1,
    float* __restrict__ gw, float* __restrict__ cst){
  int e = threadIdx.x;
  float acc = 0.f;
  for(int f=0; f<EDIM; f++) acc += bq[f]*wk[f*EDIM+e];
  float gwe = g1[e]*acc;
  gw[e] = gwe;
  float v0 = gwe;
  float v1 = b1[e]*acc + bq[e]*bk[e];
  v0 = waveSum(v0); v1 = waveSum(v1);
  __shared__ float buf[2][4];
  if((e&63)==0){ buf[0][e>>6]=v0; buf[1][e>>6]=v1; }
  __syncthreads();
  if(e==0){
    cst[0]=buf[0][0]+buf[0][1]+buf[0][2]+buf[0][3];
    cst[1]=buf[1][0]+buf[1][1]+buf[1][2]+buf[1][3];
  }
}

// ---------------------------------------------------------------------------
// k_wt: wT[ck][e][kx] = conv_w[e][c][ky][kx]   (ck = c*8+ky)
// Per-thread 8 consecutive floats -> 2x dwordx4 loads in k_conv.
// ---------------------------------------------------------------------------
__global__ __launch_bounds__(256) void k_wt(const float* __restrict__ w,
                                            float* __restrict__ wT){
  int j = blockIdx.x; int e = threadIdx.x;   // j = c*64 + ky*8 + kx
  int ck = j>>3, kx = j&7;
  wT[((size_t)ck*EDIM + e)*KF + kx] = w[(size_t)e*2048 + j];
}

// ---------------------------------------------------------------------------
// k_conv: one block per (half, oy, b). thread = output channel e.
// __launch_bounds__(256,4): min 4 waves/EU -> 128-VGPR cap. The working set
// (acc[21]+r[28]+wr[8]+addr ~ 75 regs) must live in arch VGPRs; without the
// second arg the allocator targeted 8 waves/EU (44 VGPRs) and emitted
// v_accvgpr_read/write pairs (AGPR spills) ~doubling VALU issue count.
// ---------------------------------------------------------------------------
__global__ __launch_bounds__(256, 4) void k_conv(const float* __restrict__ xc,
    const float* __restrict__ xt, const float* __restrict__ wT,
    const float* __restrict__ cbias, const float* __restrict__ gw,
    const float* __restrict__ cst, float* __restrict__ scores){
  const int half = blockIdx.x;          // 0: ox 0..20, 1: ox 20..40
  const int oy   = blockIdx.y;
  const int b    = blockIdx.z;
  const int tid  = threadIdx.x;
  const int XB   = half*20;             // window x in [XB, XB+28)
  const float* __restrict__ xb = (b<128) ? (xc + (size_t)b*CIN*HWDIM*HWDIM)
                                         : (xt + (size_t)(b-128)*CIN*HWDIM*HWDIM);
  __shared__ float band[CIN*KF*WIN];    // 7168 floats = 28 KB
  __shared__ float red[NOX][12];
  for(int k=tid;k<CIN*KF*WIN;k+=256){
    int c = k/(KF*WIN); int rem = k - c*(KF*WIN);
    int y = rem/WIN;    int xx  = rem - y*WIN;
    band[k] = xb[c*HWDIM*HWDIM + (oy+y)*HWDIM + XB + xx];
  }
  __syncthreads();

  float acc[NOX];
#pragma unroll
  for(int i=0;i<NOX;i++) acc[i]=0.f;

#pragma unroll 1
  for(int ck=0; ck<CIN*KF; ck++){
    float r[WIN];
    const float4* rp = (const float4*)&band[ck*WIN];
#pragma unroll
    for(int i=0;i<WIN/4;i++){
      float4 t = rp[i];
      r[4*i]=t.x; r[4*i+1]=t.y; r[4*i+2]=t.z; r[4*i+3]=t.w;
    }
    float wr[KF];
    const float4* wp = (const float4*)(wT + ((size_t)ck*EDIM + tid)*KF);
    {
      float4 w0 = wp[0], w1 = wp[1];
      wr[0]=w0.x; wr[1]=w0.y; wr[2]=w0.z; wr[3]=w0.w;
      wr[4]=w1.x; wr[5]=w1.y; wr[6]=w1.z; wr[7]=w1.w;
    }
#pragma unroll
    for(int kx=0;kx<KF;kx++)
#pragma unroll
      for(int ox=0;ox<NOX;ox++)
        acc[ox] += wr[kx]*r[ox+kx];
  }

  const float cb  = cbias[tid];
  const float gwe = gw[tid];
#pragma unroll 1
  for(int ox=0;ox<NOX;ox++){
    float f  = acc[ox]+cb;
    float s1 = waveSum(f);
    float s2 = waveSum(f*f);
    float s3 = waveSum(f*gwe);
    if((tid&63)==0){ int wid=tid>>6; red[ox][wid*3]=s1; red[ox][wid*3+1]=s2; red[ox][wid*3+2]=s3; }
  }
  __syncthreads();
  if(tid<NOX){
    float S1=red[tid][0]+red[tid][3]+red[tid][6]+red[tid][9];
    float S2=red[tid][1]+red[tid][4]+red[tid][7]+red[tid][10];
    float S3=red[tid][2]+red[tid][5]+red[tid][8]+red[tid][11];
    float mu  = S1*(1.f/EDIM);
    float var = S2*(1.f/EDIM) - mu*mu;
    float rs  = rsqrtf(var + EPSV);
    float sc  = (rs*(S3 - mu*cst[0]) + cst[1]) * (1.f/16.f);
    scores[(size_t)b*LPOS + oy*OW + XB + tid] = sc;   // ox=20 written by both halves (same value)
  }
}

// ---------------------------------------------------------------------------
// k_topk: per-batch exact top-4 threshold (tie-safe: select all s >= kth),
// softmax weights over selected.
// ---------------------------------------------------------------------------
__global__ __launch_bounds__(256) void k_topk(const float* __restrict__ scores,
    int* __restrict__ selIdx, float* __restrict__ selW,
    int* __restrict__ nsel, float* __restrict__ denomA){
  int b=blockIdx.x, tid=threadIdx.x;
  const float* s = scores + (size_t)b*LPOS;
  float t0=-1e30f,t1=-1e30f,t2=-1e30f,t3=-1e30f;
  for(int i=tid;i<LPOS;i+=256){
    float v=s[i];
    if(v>t3){
      if(v>t0){t3=t2;t2=t1;t1=t0;t0=v;}
      else if(v>t1){t3=t2;t2=t1;t1=v;}
      else if(v>t2){t3=t2;t2=v;}
      else t3=v;
    }
  }
  __shared__ float cand[1024];
  __shared__ float sk[2];
  __shared__ int cnt;
  cand[tid*4]=t0; cand[tid*4+1]=t1; cand[tid*4+2]=t2; cand[tid*4+3]=t3;
  __syncthreads();
  if(tid==0){
    float u0=-1e30f,u1=-1e30f,u2=-1e30f,u3=-1e30f;
    for(int i=0;i<1024;i++){
      float v=cand[i];
      if(v>u3){
        if(v>u0){u3=u2;u2=u1;u1=u0;u0=v;}
        else if(v>u1){u3=u2;u2=u1;u1=v;}
        else if(v>u2){u3=u2;u2=v;}
        else u3=v;
      }
    }
    sk[0]=u0; sk[1]=u3; cnt=0;
  }
  __syncthreads();
  float smax=sk[0], kth=sk[1];
  float part=0.f;
  for(int i=tid;i<LPOS;i+=256){
    float v=s[i];
    if(v>=kth){
      float ev=expf(v-smax);
      part+=ev;
      int p=atomicAdd(&cnt,1);
      if(p<64){ selIdx[b*64+p]=i; selW[b*64+p]=ev; }
    }
  }
  part=waveSum(part);
  __shared__ float pb[4];
  if((tid&63)==0) pb[tid>>6]=part;
  __syncthreads();
  if(tid==0){ denomA[b]=pb[0]+pb[1]+pb[2]+pb[3]; nsel[b]=cnt<64?cnt:64; }
}

// ---------------------------------------------------------------------------
// k_out: per batch, recompute fields at selected positions, v-matvec,
// attn-weighted sum, LN2, relu, write (128,512) output.
// ---------------------------------------------------------------------------
__global__ __launch_bounds__(256) void k_out(const float* __restrict__ xc,
    const float* __restrict__ xt, const float* __restrict__ wT,
    const float* __restrict__ cbias, const float* __restrict__ g1,
    const float* __restrict__ b1, const float* __restrict__ wv,
    const float* __restrict__ bv, const float* __restrict__ g2,
    const float* __restrict__ b2, const int* __restrict__ selIdx,
    const float* __restrict__ selW, const int* __restrict__ nselA,
    const float* __restrict__ denomA, float* __restrict__ out){
  int b=blockIdx.x, tid=threadIdx.x;
  const float* xb = (b<128)? (xc+(size_t)b*CIN*HWDIM*HWDIM)
                           : (xt+(size_t)(b-128)*CIN*HWDIM*HWDIM);
  __shared__ float patch[2048];
  __shared__ float fld[EDIM];
  __shared__ float rbuf[8];
  int   ns   = nselA[b];
  float dinv = 1.f/denomA[b];
  float accO = 0.f;
  for(int sI=0;sI<ns;sI++){
    int   l   = selIdx[b*64+sI];
    float wgt = selW[b*64+sI]*dinv;
    int oy=l/OW, ox=l-oy*OW;
    {
      int c=tid>>3, ky=tid&7;
      const float* src = xb + c*HWDIM*HWDIM + (oy+ky)*HWDIM + ox;
#pragma unroll
      for(int kx=0;kx<KF;kx++) patch[tid*8+kx]=src[kx];   // patch[ck*8+kx]
    }
    __syncthreads();
    float f=cbias[tid];
    for(int ck=0;ck<CIN*KF;ck++){
      const float* wrow = wT + ((size_t)ck*EDIM + tid)*KF;
#pragma unroll
      for(int kx=0;kx<KF;kx++) f += patch[ck*8+kx]*wrow[kx];
    }
    float s1=waveSum(f), s2=waveSum(f*f);
    if((tid&63)==0){ rbuf[(tid>>6)*2]=s1; rbuf[(tid>>6)*2+1]=s2; }
    __syncthreads();
    float S1=rbuf[0]+rbuf[2]+rbuf[4]+rbuf[6];
    float S2=rbuf[1]+rbuf[3]+rbuf[5]+rbuf[7];
    float mu=S1*(1.f/EDIM);
    float rs=rsqrtf(S2*(1.f/EDIM)-mu*mu+EPSV);
    fld[tid]=(f-mu)*rs*g1[tid]+b1[tid];
    __syncthreads();
    float v=bv[tid];
    const float* wr = wv + (size_t)tid*EDIM;
    for(int e2=0;e2<EDIM;e2++) v += fld[e2]*wr[e2];
    accO += wgt*v;
    __syncthreads();
  }
  float s1=waveSum(accO), s2=waveSum(accO*accO);
  if((tid&63)==0){ rbuf[(tid>>6)*2]=s1; rbuf[(tid>>6)*2+1]=s2; }
  __syncthreads();
  float S1=rbuf[0]+rbuf[2]+rbuf[4]+rbuf[6];
  float S2=rbuf[1]+rbuf[3]+rbuf[5]+rbuf[7];
  float mu=S1*(1.f/EDIM);
  float rs=rsqrtf(S2*(1.f/EDIM)-mu*mu+EPSV);
  float o=(accO-mu)*rs*g2[tid]+b2[tid];
  o = o>0.f ? o : 0.f;
  int off = (b<128)? (b*512+tid) : ((b-128)*512+256+tid);
  out[off]=o;
}

// ---------------------------------------------------------------------------
extern "C" void kernel_launch(void* const* d_in, const int* in_sizes, int n_in,
                              void* d_out, int out_size, void* d_ws, size_t ws_size,
                              hipStream_t stream){
  const float* xc = (const float*)d_in[0];
  const float* xt = (const float*)d_in[1];
  const float* cw = (const float*)d_in[2];
  const float* cb = (const float*)d_in[3];
  const float* g1 = (const float*)d_in[4];
  const float* b1 = (const float*)d_in[5];
  /* d_in[6] = wq — unused: q == bq exactly */
  const float* bq = (const float*)d_in[7];
  const float* wk = (const float*)d_in[8];
  const float* bk = (const float*)d_in[9];
  const float* wv = (const float*)d_in[10];
  const float* bv = (const float*)d_in[11];
  const float* g2 = (const float*)d_in[12];
  const float* b2 = (const float*)d_in[13];
  float* out = (float*)d_out;

  float* ws     = (float*)d_ws;
  float* wT     = ws;                      // 524288
  float* gw     = wT + 524288;             // 256
  float* cst    = gw + 256;                // 16
  float* scores = cst + 16;                // 430336
  int*   selIdx = (int*)(scores + 430336); // 256*64 ints
  float* selW   = (float*)(selIdx + 256*64);
  int*   nsel   = (int*)(selW + 256*64);
  float* denomA = (float*)(nsel + 256);

  k_prep<<<1,256,0,stream>>>(wk,bq,bk,g1,b1,gw,cst);
  k_wt<<<2048,256,0,stream>>>(cw,wT);
  dim3 g(2, OW, NB);
  k_conv<<<g,256,0,stream>>>(xc,xt,wT,cb,gw,cst,scores);
  k_topk<<<NB,256,0,stream>>>(scores,selIdx,selW,nsel,denomA);
  k_out<<<NB,256,0,stream>>>(xc,xt,wT,cb,g1,b1,wv,bv,g2,b2,selIdx,selW,nsel,denomA,out);
}

// Round 4
// 1303.967 us; speedup vs baseline: 4.6096x; 4.6096x over previous
//
#include <hip/hip_runtime.h>

#define EPSV 1e-5f

typedef float f32x4  __attribute__((ext_vector_type(4)));
typedef short bf16x8 __attribute__((ext_vector_type(8)));

__device__ __forceinline__ float waveSum(float v){
#pragma unroll
  for(int o=32;o;o>>=1) v += __shfl_xor(v,o);
  return v;
}

__device__ __forceinline__ unsigned short f2bf(float x){
  unsigned u = __builtin_bit_cast(unsigned, x);
  unsigned r = (u + 0x7FFFu + ((u>>16)&1u)) >> 16;   // round-to-nearest-even
  return (unsigned short)r;
}

// ---------------------------------------------------------------------------
// k_prep (exact fp32): gw[e] = ln1_g[e] * (sum_f bq[f]*wk[f,e]);
// cst[0] = sum_e gw[e]; cst[1] = sum_e b1[e]*wqeff[e] + bq.bk
// ---------------------------------------------------------------------------
__global__ __launch_bounds__(256) void k_prep(const float* __restrict__ wk,
    const float* __restrict__ bq, const float* __restrict__ bk,
    const float* __restrict__ g1, const float* __restrict__ b1,
    float* __restrict__ gw, float* __restrict__ cst){
  int e = threadIdx.x;
  float acc = 0.f;
  for(int f=0; f<256; f++) acc += bq[f]*wk[f*256+e];
  float gwe = g1[e]*acc;
  gw[e] = gwe;
  float v0 = gwe;
  float v1 = b1[e]*acc + bq[e]*bk[e];
  v0 = waveSum(v0); v1 = waveSum(v1);
  __shared__ float buf[2][4];
  if((e&63)==0){ buf[0][e>>6]=v0; buf[1][e>>6]=v1; }
  __syncthreads();
  if(e==0){
    cst[0]=buf[0][0]+buf[0][1]+buf[0][2]+buf[0][3];
    cst[1]=buf[1][0]+buf[1][1]+buf[1][2]+buf[1][3];
  }
}

// ---------------------------------------------------------------------------
// k_pack: Wpk[e][k] bf16, k = kx*256 + c*8 + ky  (j = c*8+ky = threadIdx)
// source conv_w[e][c][ky][kx] = w[e*2048 + j*8 + kx]
// ---------------------------------------------------------------------------
__global__ __launch_bounds__(256) void k_pack(const float* __restrict__ w,
                                              unsigned short* __restrict__ Wpk){
  int e = blockIdx.x, j = threadIdx.x;
#pragma unroll
  for (int kx = 0; kx < 8; ++kx)
    Wpk[(size_t)e*2048 + kx*256 + j] = f2bf(w[(size_t)e*2048 + j*8 + kx]);
}

// ---------------------------------------------------------------------------
// k_conv: implicit-GEMM bf16 MFMA. Block = (oy, batch-pair).
// C[e=256, col=96] = sum_K Wpk[e][K] * bandT[K][col], K=(kx,c,ky)=2048.
// bandT[bd][c][x][ky] bf16 in LDS: B-frag = aligned ds_read_b128, bank-clean.
// Epilogue: S1/S2/S3 per col -> approx score.
// ---------------------------------------------------------------------------
__global__ __launch_bounds__(256, 3) void k_conv(
    const float* __restrict__ xc, const float* __restrict__ xt,
    const unsigned short* __restrict__ Wpk,
    const float* __restrict__ cbias, const float* __restrict__ gw,
    const float* __restrict__ cst, float* __restrict__ scores){
  const int oy  = blockIdx.x;          // 0..40
  const int bp  = blockIdx.y;          // 0..127 -> batches 2bp, 2bp+1
  const int tid = threadIdx.x;
  const int lane = tid & 63;
  const int wid  = tid >> 6;           // wave 0..3 (M rows [64w,64w+64))
  const int l15  = lane & 15;
  const int l4   = lane >> 4;

  __shared__ unsigned short bandT[24704];   // 2*32*48*8 = 24576 + pad
  float* red = (float*)bandT;               // aliased after K-loop [4][6][16][3]

  // ---- stage X -> bf16 bandT ----
  for (int bd = 0; bd < 2; ++bd){
    int b = bp*2 + bd;
    const float* xb = (b < 128) ? (xc + (size_t)b*73728)
                                : (xt + (size_t)(b-128)*73728);
    for (int it = 0; it < 48; ++it){
      int idx = it*256 + tid;              // 0..12287
      int x   = idx % 48;
      int t2  = idx / 48;                  // 0..255
      int ky  = t2 & 7;
      int c   = t2 >> 3;
      float v = xb[c*2304 + (oy+ky)*48 + x];
      bandT[ ((bd*32 + c)*48 + x)*8 + ky ] = f2bf(v);
    }
  }
  __syncthreads();

  f32x4 acc[4][6];
#pragma unroll
  for (int mt=0; mt<4; ++mt)
#pragma unroll
    for (int nt=0; nt<6; ++nt) acc[mt][nt] = (f32x4){0.f,0.f,0.f,0.f};

  const unsigned short* Abase0 = Wpk + (size_t)(wid*64 +  0 + l15)*2048 + l4*8;
  const unsigned short* Abase1 = Wpk + (size_t)(wid*64 + 16 + l15)*2048 + l4*8;
  const unsigned short* Abase2 = Wpk + (size_t)(wid*64 + 32 + l15)*2048 + l4*8;
  const unsigned short* Abase3 = Wpk + (size_t)(wid*64 + 48 + l15)*2048 + l4*8;

#pragma unroll 1
  for (int kx = 0; kx < 8; ++kx){
#pragma unroll 1
    for (int cs = 0; cs < 8; ++cs){
      const int k0 = kx*256 + cs*32;
      bf16x8 a0 = *(const bf16x8*)(Abase0 + k0);
      bf16x8 a1 = *(const bf16x8*)(Abase1 + k0);
      bf16x8 a2 = *(const bf16x8*)(Abase2 + k0);
      bf16x8 a3 = *(const bf16x8*)(Abase3 + k0);
      const int c = cs*4 + l4;
#pragma unroll
      for (int nt = 0; nt < 6; ++nt){
        const int bd = nt / 3;
        const int x  = (nt % 3)*16 + l15 + kx;
        bf16x8 bf = *(const bf16x8*)&bandT[ ((bd*32 + c)*48 + x)*8 ];
        acc[0][nt] = __builtin_amdgcn_mfma_f32_16x16x32_bf16(a0, bf, acc[0][nt], 0,0,0);
        acc[1][nt] = __builtin_amdgcn_mfma_f32_16x16x32_bf16(a1, bf, acc[1][nt], 0,0,0);
        acc[2][nt] = __builtin_amdgcn_mfma_f32_16x16x32_bf16(a2, bf, acc[2][nt], 0,0,0);
        acc[3][nt] = __builtin_amdgcn_mfma_f32_16x16x32_bf16(a3, bf, acc[3][nt], 0,0,0);
      }
    }
  }

  // ---- epilogue: S1,S2,S3 per output column ----
  const float cst0 = cst[0], cst1 = cst[1];
  float s1[6], s2[6], s3[6];
#pragma unroll
  for (int nt=0;nt<6;++nt){ s1[nt]=0.f; s2[nt]=0.f; s3[nt]=0.f; }
#pragma unroll
  for (int mt=0; mt<4; ++mt){
    int eb = wid*64 + mt*16 + l4*4;       // 4 consecutive e rows of this lane
    float cb4[4], gw4[4];
    *(f32x4*)cb4 = *(const f32x4*)&cbias[eb];
    *(f32x4*)gw4 = *(const f32x4*)&gw[eb];
#pragma unroll
    for (int nt=0;nt<6;++nt){
#pragma unroll
      for (int j=0;j<4;++j){
        float f = acc[mt][nt][j] + cb4[j];
        s1[nt] += f; s2[nt] += f*f; s3[nt] += f*gw4[j];
      }
    }
  }
#pragma unroll
  for (int nt=0;nt<6;++nt){
    s1[nt] += __shfl_xor(s1[nt],16); s1[nt] += __shfl_xor(s1[nt],32);
    s2[nt] += __shfl_xor(s2[nt],16); s2[nt] += __shfl_xor(s2[nt],32);
    s3[nt] += __shfl_xor(s3[nt],16); s3[nt] += __shfl_xor(s3[nt],32);
  }
  __syncthreads();     // all K-loop LDS reads done before aliasing bandT as red
  if (l4 == 0){
#pragma unroll
    for (int nt=0;nt<6;++nt){
      int o = ((wid*6 + nt)*16 + l15)*3;
      red[o] = s1[nt]; red[o+1] = s2[nt]; red[o+2] = s3[nt];
    }
  }
  __syncthreads();
  if (tid < 96){
    int nt = tid >> 4, cl = tid & 15;
    float S1=0.f,S2=0.f,S3=0.f;
#pragma unroll
    for (int w2=0; w2<4; ++w2){
      int o = ((w2*6 + nt)*16 + cl)*3;
      S1 += red[o]; S2 += red[o+1]; S3 += red[o+2];
    }
    float mu  = S1*(1.f/256.f);
    float var = S2*(1.f/256.f) - mu*mu;
    float rs  = rsqrtf(var + EPSV);
    float sc  = (rs*(S3 - mu*cst0) + cst1)*(1.f/16.f);
    int bd = nt/3, ox = (nt%3)*16 + cl;
    if (ox < 41)
      scores[(size_t)(bp*2+bd)*1681 + oy*41 + ox] = sc;
  }
}

// ---------------------------------------------------------------------------
// k_cand: per-batch approx top-4 -> threshold - margin -> candidate list (<=32)
// ---------------------------------------------------------------------------
__global__ __launch_bounds__(256) void k_cand(const float* __restrict__ scores,
    int* __restrict__ candIdx, int* __restrict__ candN){
  int b = blockIdx.x, tid = threadIdx.x;
  const float* s = scores + (size_t)b*1681;
  float t0=-1e30f,t1=-1e30f,t2=-1e30f,t3=-1e30f;
  for (int i=tid;i<1681;i+=256){
    float v=s[i];
    if(v>t3){
      if(v>t0){t3=t2;t2=t1;t1=t0;t0=v;}
      else if(v>t1){t3=t2;t2=t1;t1=v;}
      else if(v>t2){t3=t2;t2=v;}
      else t3=v;
    }
  }
  __shared__ float cand[1024];
  __shared__ float kth4;
  __shared__ int cnt;
  cand[tid*4]=t0; cand[tid*4+1]=t1; cand[tid*4+2]=t2; cand[tid*4+3]=t3;
  __syncthreads();
  if(tid==0){
    float u0=-1e30f,u1=-1e30f,u2=-1e30f,u3=-1e30f;
    for(int i=0;i<1024;i++){
      float v=cand[i];
      if(v>u3){
        if(v>u0){u3=u2;u2=u1;u1=u0;u0=v;}
        else if(v>u1){u3=u2;u2=u1;u1=v;}
        else if(v>u2){u3=u2;u2=v;}
        else u3=v;
      }
    }
    kth4=u3; cnt=0;
  }
  __syncthreads();
  float thr = kth4 - 4e-3f;    // margin >> bf16 score error (~1e-4)
  for (int i=tid;i<1681;i+=256){
    if (s[i] >= thr){
      int p = atomicAdd(&cnt,1);
      if (p < 32) candIdx[b*32+p] = i;
    }
  }
  __syncthreads();
  if (tid==0) candN[b] = cnt<32?cnt:32;
}

// ---------------------------------------------------------------------------
// k_final: exact fp32 rescore of candidates (groups of 4), exact top-4 +
// softmax, exact v-accum, LN2, relu, out. Output == pure-fp32 path.
// ---------------------------------------------------------------------------
__global__ __launch_bounds__(256) void k_final(
    const float* __restrict__ xc, const float* __restrict__ xt,
    const float* __restrict__ cw, const float* __restrict__ cbias,
    const float* __restrict__ g1, const float* __restrict__ b1,
    const float* __restrict__ wvm, const float* __restrict__ bv,
    const float* __restrict__ g2, const float* __restrict__ b2,
    const float* __restrict__ gw, const float* __restrict__ cst,
    const int* __restrict__ candIdx, const int* __restrict__ candN,
    float* __restrict__ out){
  const int b = blockIdx.x, tid = threadIdx.x;
  const float* xb = (b<128) ? (xc + (size_t)b*73728)
                            : (xt + (size_t)(b-128)*73728);
  __shared__ float fpatch[4][2048];
  __shared__ float scsh[32];
  __shared__ float rbuf[12];
  __shared__ float fld[256];
  __shared__ float sel[3];
  const int nc = candN[b];
  const float cst0 = cst[0], cst1 = cst[1];
  const float gwe = gw[tid], cbe = cbias[tid];
  const float* wr = cw + (size_t)tid*2048;

  // ---- pass 1: exact scores for all candidates ----
  for (int g0 = 0; g0 < nc; g0 += 4){
    int gn = nc - g0; if (gn > 4) gn = 4;
    __syncthreads();
    for (int ci = 0; ci < gn; ++ci){
      int l = candIdx[b*32 + g0 + ci];
      int oyy = l/41, oxx = l - oyy*41;
      const float* src = xb + (tid>>3)*2304 + (oyy + (tid&7))*48 + oxx;
#pragma unroll
      for (int kx=0;kx<8;++kx) fpatch[ci][tid*8+kx] = src[kx];
    }
    __syncthreads();
    float f0=cbe,f1=cbe,f2=cbe,f3=cbe;
    for (int q=0;q<512;++q){
      float4 wq = ((const float4*)wr)[q];
      float4 p0 = ((const float4*)fpatch[0])[q];
      float4 p1 = ((const float4*)fpatch[1])[q];
      float4 p2 = ((const float4*)fpatch[2])[q];
      float4 p3 = ((const float4*)fpatch[3])[q];
      f0 += wq.x*p0.x + wq.y*p0.y + wq.z*p0.z + wq.w*p0.w;
      f1 += wq.x*p1.x + wq.y*p1.y + wq.z*p1.z + wq.w*p1.w;
      f2 += wq.x*p2.x + wq.y*p2.y + wq.z*p2.z + wq.w*p2.w;
      f3 += wq.x*p3.x + wq.y*p3.y + wq.z*p3.z + wq.w*p3.w;
    }
#pragma unroll
    for (int ci=0; ci<4; ++ci){
      if (ci >= gn) break;
      float f = (ci==0)?f0:(ci==1)?f1:(ci==2)?f2:f3;
      float a1 = waveSum(f), a2 = waveSum(f*f), a3 = waveSum(f*gwe);
      if ((tid&63)==0){ int wd=tid>>6; rbuf[wd*3]=a1; rbuf[wd*3+1]=a2; rbuf[wd*3+2]=a3; }
      __syncthreads();
      if (tid==0){
        float S1=rbuf[0]+rbuf[3]+rbuf[6]+rbuf[9];
        float S2=rbuf[1]+rbuf[4]+rbuf[7]+rbuf[10];
        float S3=rbuf[2]+rbuf[5]+rbuf[8]+rbuf[11];
        float mu=S1*(1.f/256.f);
        float rs=rsqrtf(S2*(1.f/256.f)-mu*mu+EPSV);
        scsh[g0+ci] = (rs*(S3-mu*cst0)+cst1)*(1.f/16.f);
      }
      __syncthreads();
    }
  }
  // ---- exact top-4 (with multiplicity) + softmax constants ----
  if (tid == 0){
    float u0=-1e30f,u1=-1e30f,u2=-1e30f,u3=-1e30f;
    for (int i=0;i<nc;++i){
      float v=scsh[i];
      if(v>u3){
        if(v>u0){u3=u2;u2=u1;u1=u0;u0=v;}
        else if(v>u1){u3=u2;u2=u1;u1=v;}
        else if(v>u2){u3=u2;u2=v;}
        else u3=v;
      }
    }
    float den = 0.f;
    for (int i=0;i<nc;++i) if (scsh[i] >= u3) den += expf(scsh[i]-u0);
    sel[0]=u3; sel[1]=u0; sel[2]=den;
  }
  __syncthreads();
  const float kthv=sel[0], smax=sel[1], dinv=1.f/sel[2];

  // ---- pass 2: recompute f for groups, accumulate weighted v for selected --
  float accO = 0.f;
  for (int g0 = 0; g0 < nc; g0 += 4){
    int gn = nc - g0; if (gn > 4) gn = 4;
    __syncthreads();
    for (int ci = 0; ci < gn; ++ci){
      int l = candIdx[b*32 + g0 + ci];
      int oyy = l/41, oxx = l - oyy*41;
      const float* src = xb + (tid>>3)*2304 + (oyy + (tid&7))*48 + oxx;
#pragma unroll
      for (int kx=0;kx<8;++kx) fpatch[ci][tid*8+kx] = src[kx];
    }
    __syncthreads();
    float f0=cbe,f1=cbe,f2=cbe,f3=cbe;
    for (int q=0;q<512;++q){
      float4 wq = ((const float4*)wr)[q];
      float4 p0 = ((const float4*)fpatch[0])[q];
      float4 p1 = ((const float4*)fpatch[1])[q];
      float4 p2 = ((const float4*)fpatch[2])[q];
      float4 p3 = ((const float4*)fpatch[3])[q];
      f0 += wq.x*p0.x + wq.y*p0.y + wq.z*p0.z + wq.w*p0.w;
      f1 += wq.x*p1.x + wq.y*p1.y + wq.z*p1.z + wq.w*p1.w;
      f2 += wq.x*p2.x + wq.y*p2.y + wq.z*p2.z + wq.w*p2.w;
      f3 += wq.x*p3.x + wq.y*p3.y + wq.z*p3.z + wq.w*p3.w;
    }
#pragma unroll
    for (int ci=0; ci<4; ++ci){
      if (ci >= gn) break;
      float sc = scsh[g0+ci];
      if (sc >= kthv){
        float wgt = expf(sc - smax)*dinv;
        float f = (ci==0)?f0:(ci==1)?f1:(ci==2)?f2:f3;
        float a1 = waveSum(f), a2 = waveSum(f*f);
        if ((tid&63)==0){ int wd=tid>>6; rbuf[wd*3]=a1; rbuf[wd*3+1]=a2; }
        __syncthreads();
        float S1=rbuf[0]+rbuf[3]+rbuf[6]+rbuf[9];
        float S2=rbuf[1]+rbuf[4]+rbuf[7]+rbuf[10];
        float mu=S1*(1.f/256.f);
        float rs=rsqrtf(S2*(1.f/256.f)-mu*mu+EPSV);
        fld[tid] = (f-mu)*rs*g1[tid]+b1[tid];
        __syncthreads();
        float vv = bv[tid];
        const float* wrow = wvm + (size_t)tid*256;
        for (int q=0;q<64;++q){
          float4 w4 = ((const float4*)wrow)[q];
          float4 f4 = ((const float4*)fld)[q];
          vv += w4.x*f4.x + w4.y*f4.y + w4.z*f4.z + w4.w*f4.w;
        }
        accO += wgt*vv;
        __syncthreads();
      }
    }
  }
  // ---- LN2 + relu + write ----
  {
    float a1=waveSum(accO), a2=waveSum(accO*accO);
    if((tid&63)==0){ int wd=tid>>6; rbuf[wd*3]=a1; rbuf[wd*3+1]=a2; }
    __syncthreads();
    float S1=rbuf[0]+rbuf[3]+rbuf[6]+rbuf[9];
    float S2=rbuf[1]+rbuf[4]+rbuf[7]+rbuf[10];
    float mu=S1*(1.f/256.f);
    float rs=rsqrtf(S2*(1.f/256.f)-mu*mu+EPSV);
    float o=(accO-mu)*rs*g2[tid]+b2[tid];
    o = o>0.f ? o : 0.f;
    int off = (b<128)? (b*512+tid) : ((b-128)*512+256+tid);
    out[off]=o;
  }
}

// ---------------------------------------------------------------------------
extern "C" void kernel_launch(void* const* d_in, const int* in_sizes, int n_in,
                              void* d_out, int out_size, void* d_ws, size_t ws_size,
                              hipStream_t stream){
  const float* xc = (const float*)d_in[0];
  const float* xt = (const float*)d_in[1];
  const float* cw = (const float*)d_in[2];
  const float* cb = (const float*)d_in[3];
  const float* g1 = (const float*)d_in[4];
  const float* b1 = (const float*)d_in[5];
  /* d_in[6] = wq — unused: q == bq exactly */
  const float* bq = (const float*)d_in[7];
  const float* wk = (const float*)d_in[8];
  const float* bk = (const float*)d_in[9];
  const float* wvp= (const float*)d_in[10];
  const float* bv = (const float*)d_in[11];
  const float* g2 = (const float*)d_in[12];
  const float* b2 = (const float*)d_in[13];
  float* out = (float*)d_out;

  unsigned short* Wpk = (unsigned short*)d_ws;          // 524288 ushorts (1 MB)
  float* gw     = (float*)d_ws + 262144;                // 256
  float* cst    = gw + 256;                             // 16
  float* scores = cst + 16;                             // 256*1681 = 430336
  int*   candIdx= (int*)(scores + 430336);              // 256*32
  int*   candN  = candIdx + 256*32;                     // 256

  k_prep<<<1,256,0,stream>>>(wk,bq,bk,g1,b1,gw,cst);
  k_pack<<<256,256,0,stream>>>(cw,Wpk);
  k_conv<<<dim3(41,128),256,0,stream>>>(xc,xt,Wpk,cb,gw,cst,scores);
  k_cand<<<256,256,0,stream>>>(scores,candIdx,candN);
  k_final<<<256,256,0,stream>>>(xc,xt,cw,cb,g1,b1,wvp,bv,g2,b2,gw,cst,candIdx,candN,out);
}

// Round 5
// 1042.827 us; speedup vs baseline: 5.7639x; 1.2504x over previous
//
#include <hip/hip_runtime.h>

#define EPSV 1e-5f

typedef float f32x4  __attribute__((ext_vector_type(4)));
typedef short bf16x8 __attribute__((ext_vector_type(8)));

__device__ __forceinline__ float waveSum(float v){
#pragma unroll
  for(int o=32;o;o>>=1) v += __shfl_xor(v,o);
  return v;
}

__device__ __forceinline__ unsigned short f2bf(float x){
  unsigned u = __builtin_bit_cast(unsigned, x);
  unsigned r = (u + 0x7FFFu + ((u>>16)&1u)) >> 16;   // round-to-nearest-even
  return (unsigned short)r;
}

// ---------------------------------------------------------------------------
// k_prep (exact fp32): gw[e] = ln1_g[e] * (sum_f bq[f]*wk[f,e]);
// cst[0] = sum_e gw[e]; cst[1] = sum_e b1[e]*wqeff[e] + bq.bk
// ---------------------------------------------------------------------------
__global__ __launch_bounds__(256) void k_prep(const float* __restrict__ wk,
    const float* __restrict__ bq, const float* __restrict__ bk,
    const float* __restrict__ g1, const float* __restrict__ b1,
    float* __restrict__ gw, float* __restrict__ cst){
  int e = threadIdx.x;
  float acc = 0.f;
  for(int f=0; f<256; f++) acc += bq[f]*wk[f*256+e];
  float gwe = g1[e]*acc;
  gw[e] = gwe;
  float v0 = gwe;
  float v1 = b1[e]*acc + bq[e]*bk[e];
  v0 = waveSum(v0); v1 = waveSum(v1);
  __shared__ float buf[2][4];
  if((e&63)==0){ buf[0][e>>6]=v0; buf[1][e>>6]=v1; }
  __syncthreads();
  if(e==0){
    cst[0]=buf[0][0]+buf[0][1]+buf[0][2]+buf[0][3];
    cst[1]=buf[1][0]+buf[1][1]+buf[1][2]+buf[1][3];
  }
}

// ---------------------------------------------------------------------------
// k_pack: Wpk[e][k] bf16, k = kx*256 + c*8 + ky  (j = c*8+ky = threadIdx)
// ---------------------------------------------------------------------------
__global__ __launch_bounds__(256) void k_pack(const float* __restrict__ w,
                                              unsigned short* __restrict__ Wpk){
  int e = blockIdx.x, j = threadIdx.x;
#pragma unroll
  for (int kx = 0; kx < 8; ++kx)
    Wpk[(size_t)e*2048 + kx*256 + j] = f2bf(w[(size_t)e*2048 + j*8 + kx]);
}

// ---------------------------------------------------------------------------
// k_conv: implicit-GEMM bf16 MFMA. Block = (oy, batch-pair).
// Flattened 64-step K-loop; A-frags register-double-buffered so the L2 load
// latency of step k+1 hides under step k's 24 MFMAs (466 SIMD-cyc).
// ---------------------------------------------------------------------------
__global__ __launch_bounds__(256, 3) void k_conv(
    const float* __restrict__ xc, const float* __restrict__ xt,
    const unsigned short* __restrict__ Wpk,
    const float* __restrict__ cbias, const float* __restrict__ gw,
    const float* __restrict__ cst, float* __restrict__ scores){
  const int oy  = blockIdx.x;          // 0..40
  const int bp  = blockIdx.y;          // 0..127 -> batches 2bp, 2bp+1
  const int tid = threadIdx.x;
  const int lane = tid & 63;
  const int wid  = tid >> 6;           // wave 0..3 (M rows [64w,64w+64))
  const int l15  = lane & 15;
  const int l4   = lane >> 4;

  __shared__ unsigned short bandT[24704];   // 2*32*48*8 = 24576 + pad
  float* red = (float*)bandT;               // aliased after K-loop

  // ---- stage X -> bf16 bandT ----
  for (int bd = 0; bd < 2; ++bd){
    int b = bp*2 + bd;
    const float* xb = (b < 128) ? (xc + (size_t)b*73728)
                                : (xt + (size_t)(b-128)*73728);
    for (int it = 0; it < 48; ++it){
      int idx = it*256 + tid;              // 0..12287
      int x   = idx % 48;
      int t2  = idx / 48;                  // 0..255
      int ky  = t2 & 7;
      int c   = t2 >> 3;
      float v = xb[c*2304 + (oy+ky)*48 + x];
      bandT[ ((bd*32 + c)*48 + x)*8 + ky ] = f2bf(v);
    }
  }
  __syncthreads();

  f32x4 acc[4][6];
#pragma unroll
  for (int mt=0; mt<4; ++mt)
#pragma unroll
    for (int nt=0; nt<6; ++nt) acc[mt][nt] = (f32x4){0.f,0.f,0.f,0.f};

  const unsigned short* Ab[4];
#pragma unroll
  for (int mt=0; mt<4; ++mt)
    Ab[mt] = Wpk + (size_t)(wid*64 + mt*16 + l15)*2048 + l4*8;

  bf16x8 a_cur[4];
#pragma unroll
  for (int mt=0; mt<4; ++mt) a_cur[mt] = *(const bf16x8*)(Ab[mt]);

#pragma unroll 1
  for (int ks = 0; ks < 64; ++ks){
    // prefetch next step's A-frags (vmcnt wait lands under this step's MFMAs)
    const int ksn = (ks+1 < 64) ? (ks+1) : 63;
    bf16x8 a_nxt[4];
#pragma unroll
    for (int mt=0; mt<4; ++mt) a_nxt[mt] = *(const bf16x8*)(Ab[mt] + ksn*32);

    const int kx = ks >> 3, cs = ks & 7;
    const int c  = cs*4 + l4;
    // B-frags grouped first, then the MFMA cluster
    bf16x8 bfr[6];
#pragma unroll
    for (int nt = 0; nt < 6; ++nt){
      const int bd = nt / 3;
      const int x  = (nt % 3)*16 + l15 + kx;
      bfr[nt] = *(const bf16x8*)&bandT[ ((bd*32 + c)*48 + x)*8 ];
    }
#pragma unroll
    for (int nt = 0; nt < 6; ++nt){
      acc[0][nt] = __builtin_amdgcn_mfma_f32_16x16x32_bf16(a_cur[0], bfr[nt], acc[0][nt], 0,0,0);
      acc[1][nt] = __builtin_amdgcn_mfma_f32_16x16x32_bf16(a_cur[1], bfr[nt], acc[1][nt], 0,0,0);
      acc[2][nt] = __builtin_amdgcn_mfma_f32_16x16x32_bf16(a_cur[2], bfr[nt], acc[2][nt], 0,0,0);
      acc[3][nt] = __builtin_amdgcn_mfma_f32_16x16x32_bf16(a_cur[3], bfr[nt], acc[3][nt], 0,0,0);
    }
#pragma unroll
    for (int mt=0; mt<4; ++mt) a_cur[mt] = a_nxt[mt];
  }

  // ---- epilogue: S1,S2,S3 per output column ----
  const float cst0 = cst[0], cst1 = cst[1];
  float s1[6], s2[6], s3[6];
#pragma unroll
  for (int nt=0;nt<6;++nt){ s1[nt]=0.f; s2[nt]=0.f; s3[nt]=0.f; }
#pragma unroll
  for (int mt=0; mt<4; ++mt){
    int eb = wid*64 + mt*16 + l4*4;       // 4 consecutive e rows of this lane
    float cb4[4], gw4[4];
    *(f32x4*)cb4 = *(const f32x4*)&cbias[eb];
    *(f32x4*)gw4 = *(const f32x4*)&gw[eb];
#pragma unroll
    for (int nt=0;nt<6;++nt){
#pragma unroll
      for (int j=0;j<4;++j){
        float f = acc[mt][nt][j] + cb4[j];
        s1[nt] += f; s2[nt] += f*f; s3[nt] += f*gw4[j];
      }
    }
  }
#pragma unroll
  for (int nt=0;nt<6;++nt){
    s1[nt] += __shfl_xor(s1[nt],16); s1[nt] += __shfl_xor(s1[nt],32);
    s2[nt] += __shfl_xor(s2[nt],16); s2[nt] += __shfl_xor(s2[nt],32);
    s3[nt] += __shfl_xor(s3[nt],16); s3[nt] += __shfl_xor(s3[nt],32);
  }
  __syncthreads();     // all K-loop LDS reads done before aliasing bandT as red
  if (l4 == 0){
#pragma unroll
    for (int nt=0;nt<6;++nt){
      int o = ((wid*6 + nt)*16 + l15)*3;
      red[o] = s1[nt]; red[o+1] = s2[nt]; red[o+2] = s3[nt];
    }
  }
  __syncthreads();
  if (tid < 96){
    int nt = tid >> 4, cl = tid & 15;
    float S1=0.f,S2=0.f,S3=0.f;
#pragma unroll
    for (int w2=0; w2<4; ++w2){
      int o = ((w2*6 + nt)*16 + cl)*3;
      S1 += red[o]; S2 += red[o+1]; S3 += red[o+2];
    }
    float mu  = S1*(1.f/256.f);
    float var = S2*(1.f/256.f) - mu*mu;
    float rs  = rsqrtf(var + EPSV);
    float sc  = (rs*(S3 - mu*cst0) + cst1)*(1.f/16.f);
    int bd = nt/3, ox = (nt%3)*16 + cl;
    if (ox < 41)
      scores[(size_t)(bp*2+bd)*1681 + oy*41 + ox] = sc;
  }
}

// ---------------------------------------------------------------------------
// k_cand: per-batch approx top-4 -> threshold - margin -> candidate list (<=16)
// ---------------------------------------------------------------------------
__global__ __launch_bounds__(256) void k_cand(const float* __restrict__ scores,
    int* __restrict__ candIdx, int* __restrict__ candN){
  int b = blockIdx.x, tid = threadIdx.x;
  const float* s = scores + (size_t)b*1681;
  float t0=-1e30f,t1=-1e30f,t2=-1e30f,t3=-1e30f;
  for (int i=tid;i<1681;i+=256){
    float v=s[i];
    if(v>t3){
      if(v>t0){t3=t2;t2=t1;t1=t0;t0=v;}
      else if(v>t1){t3=t2;t2=t1;t1=v;}
      else if(v>t2){t3=t2;t2=v;}
      else t3=v;
    }
  }
  __shared__ float cand[1024];
  __shared__ float kth4;
  __shared__ int cnt;
  cand[tid*4]=t0; cand[tid*4+1]=t1; cand[tid*4+2]=t2; cand[tid*4+3]=t3;
  __syncthreads();
  if(tid==0){
    float u0=-1e30f,u1=-1e30f,u2=-1e30f,u3=-1e30f;
    for(int i=0;i<1024;i++){
      float v=cand[i];
      if(v>u3){
        if(v>u0){u3=u2;u2=u1;u1=u0;u0=v;}
        else if(v>u1){u3=u2;u2=u1;u1=v;}
        else if(v>u2){u3=u2;u2=v;}
        else u3=v;
      }
    }
    kth4=u3; cnt=0;
  }
  __syncthreads();
  float thr = kth4 - 4e-3f;    // margin ~28 sigma of bf16 score error
  for (int i=tid;i<1681;i+=256){
    if (s[i] >= thr){
      int p = atomicAdd(&cnt,1);
      if (p < 16) candIdx[b*32+p] = i;
    }
  }
  __syncthreads();
  if (tid==0) candN[b] = cnt<16?cnt:16;
}

// ---------------------------------------------------------------------------
// k_final: exact fp32 rescore of candidates; f cached in LDS so the selected
// accumulation pass does ZERO conv recomputes. Output == pure-fp32 path.
// ---------------------------------------------------------------------------
__global__ __launch_bounds__(256) void k_final(
    const float* __restrict__ xc, const float* __restrict__ xt,
    const float* __restrict__ cw, const float* __restrict__ cbias,
    const float* __restrict__ g1, const float* __restrict__ b1,
    const float* __restrict__ wvm, const float* __restrict__ bv,
    const float* __restrict__ g2, const float* __restrict__ b2,
    const float* __restrict__ gw, const float* __restrict__ cst,
    const int* __restrict__ candIdx, const int* __restrict__ candN,
    float* __restrict__ out){
  const int b = blockIdx.x, tid = threadIdx.x;
  const float* xb = (b<128) ? (xc + (size_t)b*73728)
                            : (xt + (size_t)(b-128)*73728);
  __shared__ float fpatch[4][2048];   // 32 KB
  __shared__ float fcache[16][256];   // 16 KB: exact f per candidate
  __shared__ float scsh[16];
  __shared__ float rbuf[12];
  __shared__ float sel[3];
  int nc = candN[b]; if (nc > 16) nc = 16;
  const float cst0 = cst[0], cst1 = cst[1];
  const float gwe = gw[tid], cbe = cbias[tid];
  const float* wr = cw + (size_t)tid*2048;

  // ---- pass 1: exact f + score for all candidates ----
  for (int g0 = 0; g0 < nc; g0 += 4){
    int gn = nc - g0; if (gn > 4) gn = 4;
    __syncthreads();
    for (int ci = 0; ci < gn; ++ci){
      int l = candIdx[b*32 + g0 + ci];
      int oyy = l/41, oxx = l - oyy*41;
      const float* src = xb + (tid>>3)*2304 + (oyy + (tid&7))*48 + oxx;
#pragma unroll
      for (int kx=0;kx<8;++kx) fpatch[ci][tid*8+kx] = src[kx];
    }
    __syncthreads();
    float f0=cbe,f1=cbe,f2=cbe,f3=cbe;
    for (int q=0;q<512;++q){
      float4 wq = ((const float4*)wr)[q];
      float4 p0 = ((const float4*)fpatch[0])[q];
      float4 p1 = ((const float4*)fpatch[1])[q];
      float4 p2 = ((const float4*)fpatch[2])[q];
      float4 p3 = ((const float4*)fpatch[3])[q];
      f0 += wq.x*p0.x + wq.y*p0.y + wq.z*p0.z + wq.w*p0.w;
      f1 += wq.x*p1.x + wq.y*p1.y + wq.z*p1.z + wq.w*p1.w;
      f2 += wq.x*p2.x + wq.y*p2.y + wq.z*p2.z + wq.w*p2.w;
      f3 += wq.x*p3.x + wq.y*p3.y + wq.z*p3.z + wq.w*p3.w;
    }
#pragma unroll
    for (int ci=0; ci<4; ++ci){
      if (ci >= gn) break;
      float f = (ci==0)?f0:(ci==1)?f1:(ci==2)?f2:f3;
      fcache[g0+ci][tid] = f;
      float a1 = waveSum(f), a2 = waveSum(f*f), a3 = waveSum(f*gwe);
      if ((tid&63)==0){ int wd=tid>>6; rbuf[wd*3]=a1; rbuf[wd*3+1]=a2; rbuf[wd*3+2]=a3; }
      __syncthreads();
      if (tid==0){
        float S1=rbuf[0]+rbuf[3]+rbuf[6]+rbuf[9];
        float S2=rbuf[1]+rbuf[4]+rbuf[7]+rbuf[10];
        float S3=rbuf[2]+rbuf[5]+rbuf[8]+rbuf[11];
        float mu=S1*(1.f/256.f);
        float rs=rsqrtf(S2*(1.f/256.f)-mu*mu+EPSV);
        scsh[g0+ci] = (rs*(S3-mu*cst0)+cst1)*(1.f/16.f);
      }
      __syncthreads();
    }
  }
  // ---- exact top-4 (with multiplicity) + softmax constants ----
  if (tid == 0){
    float u0=-1e30f,u1=-1e30f,u2=-1e30f,u3=-1e30f;
    for (int i=0;i<nc;++i){
      float v=scsh[i];
      if(v>u3){
        if(v>u0){u3=u2;u2=u1;u1=u0;u0=v;}
        else if(v>u1){u3=u2;u2=u1;u1=v;}
        else if(v>u2){u3=u2;u2=v;}
        else u3=v;
      }
    }
    float den = 0.f;
    for (int i=0;i<nc;++i) if (scsh[i] >= u3) den += expf(scsh[i]-u0);
    sel[0]=u3; sel[1]=u0; sel[2]=den;
  }
  __syncthreads();
  const float kthv=sel[0], smax=sel[1], dinv=1.f/sel[2];

  // ---- pass 2: selected only, f from cache (no conv recompute) ----
  float accO = 0.f;
  float* fld = fpatch[0];
  for (int i = 0; i < nc; ++i){
    float sc = scsh[i];
    if (sc >= kthv){                         // uniform branch (scsh shared)
      float wgt = expf(sc - smax)*dinv;
      float f = fcache[i][tid];
      float a1 = waveSum(f), a2 = waveSum(f*f);
      if ((tid&63)==0){ int wd=tid>>6; rbuf[wd*3]=a1; rbuf[wd*3+1]=a2; }
      __syncthreads();
      float S1=rbuf[0]+rbuf[3]+rbuf[6]+rbuf[9];
      float S2=rbuf[1]+rbuf[4]+rbuf[7]+rbuf[10];
      float mu=S1*(1.f/256.f);
      float rs=rsqrtf(S2*(1.f/256.f)-mu*mu+EPSV);
      fld[tid] = (f-mu)*rs*g1[tid]+b1[tid];
      __syncthreads();
      float vv = bv[tid];
      const float* wrow = wvm + (size_t)tid*256;
      for (int q=0;q<64;++q){
        float4 w4 = ((const float4*)wrow)[q];
        float4 f4 = ((const float4*)fld)[q];
        vv += w4.x*f4.x + w4.y*f4.y + w4.z*f4.z + w4.w*f4.w;
      }
      accO += wgt*vv;
      __syncthreads();
    }
  }
  // ---- LN2 + relu + write ----
  {
    float a1=waveSum(accO), a2=waveSum(accO*accO);
    if((tid&63)==0){ int wd=tid>>6; rbuf[wd*3]=a1; rbuf[wd*3+1]=a2; }
    __syncthreads();
    float S1=rbuf[0]+rbuf[3]+rbuf[6]+rbuf[9];
    float S2=rbuf[1]+rbuf[4]+rbuf[7]+rbuf[10];
    float mu=S1*(1.f/256.f);
    float rs=rsqrtf(S2*(1.f/256.f)-mu*mu+EPSV);
    float o=(accO-mu)*rs*g2[tid]+b2[tid];
    o = o>0.f ? o : 0.f;
    int off = (b<128)? (b*512+tid) : ((b-128)*512+256+tid);
    out[off]=o;
  }
}

// ---------------------------------------------------------------------------
extern "C" void kernel_launch(void* const* d_in, const int* in_sizes, int n_in,
                              void* d_out, int out_size, void* d_ws, size_t ws_size,
                              hipStream_t stream){
  const float* xc = (const float*)d_in[0];
  const float* xt = (const float*)d_in[1];
  const float* cw = (const float*)d_in[2];
  const float* cb = (const float*)d_in[3];
  const float* g1 = (const float*)d_in[4];
  const float* b1 = (const float*)d_in[5];
  /* d_in[6] = wq — unused: q == bq exactly */
  const float* bq = (const float*)d_in[7];
  const float* wk = (const float*)d_in[8];
  const float* bk = (const float*)d_in[9];
  const float* wvp= (const float*)d_in[10];
  const float* bv = (const float*)d_in[11];
  const float* g2 = (const float*)d_in[12];
  const float* b2 = (const float*)d_in[13];
  float* out = (float*)d_out;

  unsigned short* Wpk = (unsigned short*)d_ws;          // 524288 ushorts (1 MB)
  float* gw     = (float*)d_ws + 262144;                // 256
  float* cst    = gw + 256;                             // 16
  float* scores = cst + 16;                             // 256*1681 = 430336
  int*   candIdx= (int*)(scores + 430336);              // 256*32
  int*   candN  = candIdx + 256*32;                     // 256

  k_prep<<<1,256,0,stream>>>(wk,bq,bk,g1,b1,gw,cst);
  k_pack<<<256,256,0,stream>>>(cw,Wpk);
  k_conv<<<dim3(41,128),256,0,stream>>>(xc,xt,Wpk,cb,gw,cst,scores);
  k_cand<<<256,256,0,stream>>>(scores,candIdx,candN);
  k_final<<<256,256,0,stream>>>(xc,xt,cw,cb,g1,b1,wvp,bv,g2,b2,gw,cst,candIdx,candN,out);
}